// Round 22
// baseline (60.095 us; speedup 1.0000x reference)
//
#include <hip/hip_runtime.h>

#define TID threadIdx.x

constexpr int B = 2, C = 256, N = 2048, H = 8, D = 32, BH = 16;
constexpr float EPS = 1e-5f;
constexpr float SCL2 = 0.25505654344454694f; // 32^-0.5 * log2(e)
constexpr size_t SZ = (size_t)BH * N * D;    // 1048576 elements per Q/K/V buffer

typedef _Float16 h8 __attribute__((ext_vector_type(8)));
typedef _Float16 h4 __attribute__((ext_vector_type(4)));
typedef __fp16 fp16x2 __attribute__((ext_vector_type(2)));
typedef float f32x4 __attribute__((ext_vector_type(4)));

// ---------------- kernel 1: batchnorm stats, BN-FOLDED: a = rstd*gamma, bb = beta - mean*a
__global__ __launch_bounds__(256) void k_bnstats(const float* __restrict__ x,
                                                 const float* __restrict__ gamma,
                                                 const float* __restrict__ beta,
                                                 float* __restrict__ stats) {
  int c = blockIdx.x;
  float s = 0.f, ss = 0.f;
  const float4* x4 = (const float4*)x;
  for (int k = 0; k < B; ++k) {
    const float4* p = x4 + (size_t)(k * C + c) * (N / 4);
    for (int i = TID; i < N / 4; i += 256) {
      float4 v = p[i];
      s += v.x + v.y + v.z + v.w;
      ss += v.x * v.x + v.y * v.y + v.z * v.z + v.w * v.w;
    }
  }
#pragma unroll
  for (int off = 32; off; off >>= 1) {
    s += __shfl_down(s, off);
    ss += __shfl_down(ss, off);
  }
  __shared__ float red[8];
  int w = TID >> 6;
  if ((TID & 63) == 0) { red[w] = s; red[4 + w] = ss; }
  __syncthreads();
  if (TID == 0) {
    float S = red[0] + red[1] + red[2] + red[3];
    float SS = red[4] + red[5] + red[6] + red[7];
    float mean = S * (1.f / (B * N));
    float var = SS * (1.f / (B * N)) - mean * mean;
    float a = rsqrtf(var + EPS) * gamma[c];
    stats[c] = a;
    stats[C + c] = beta[c] - mean * a;
  }
}

// ---------------- kernel 2: proj v3 — DS-minimized; Q pre-scaled by SCL2 ----------------
__global__ __launch_bounds__(256) void k_proj(const float* __restrict__ x,
    const float* __restrict__ wk, const float* __restrict__ wq,
    const float* __restrict__ wv, const float* __restrict__ stats,
    _Float16* __restrict__ qa, _Float16* __restrict__ ka, _Float16* __restrict__ va) {
  int proj = blockIdx.x >> 8;
  int rem = blockIdx.x & 255;
  int b = rem >> 7;
  int n0 = (rem & 127) * 16;
  const float* w = proj == 0 ? wk : (proj == 1 ? wq : wv);
  _Float16* out = proj == 0 ? qa : (proj == 1 ? ka : va);
  float qs = (proj == 0) ? SCL2 : 1.0f;  // fold attention scale into Q

  __shared__ float w_t[32 * 264];  // [c][ch] transposed weights (+8 pad)
  __shared__ float xs[256 * 18];   // row (g+8c); col' = col ^ ((((row)>>4)&3)<<2)
  __shared__ float sab[512];       // a[c], bb[c]

  sab[TID] = stats[TID];
  sab[256 + TID] = stats[256 + TID];
  {
    const float4* wr4 = (const float4*)(w + TID * 32);
#pragma unroll
    for (int p = 0; p < 8; ++p) {
      float4 v = wr4[p];
      w_t[(p * 4 + 0) * 264 + TID] = v.x;
      w_t[(p * 4 + 1) * 264 + TID] = v.y;
      w_t[(p * 4 + 2) * 264 + TID] = v.z;
      w_t[(p * 4 + 3) * 264 + TID] = v.w;
    }
  }
  __syncthreads();
#pragma unroll
  for (int p = 0; p < 4; ++p) {
    int c = p * 64 + (TID >> 2);
    int n4 = (TID & 3) * 4;
    float4 v = *(const float4*)(x + (size_t)(b * C + c) * N + n0 + n4);
    float a = sab[c], bb = sab[256 + c];
    int row = (c >> 5) + ((c & 31) << 3);  // g + 8c
    int swz = ((row >> 4) & 3) << 2;
    float2 lo = {v.x * a + bb, v.y * a + bb};
    float2 hi = {v.z * a + bb, v.w * a + bb};
    *(float2*)&xs[row * 18 + (n4 ^ swz)] = lo;
    *(float2*)&xs[row * 18 + ((n4 + 2) ^ swz)] = hi;
  }
  __syncthreads();

  int d = TID & 31, t2 = TID >> 5;
  int g = d >> 2;  // channel group, h-invariant
  float2 acc[8];
#pragma unroll
  for (int h = 0; h < 8; ++h) acc[h] = (float2){0.f, 0.f};
#pragma unroll
  for (int c = 0; c < 32; ++c) {
    float4 w0 = *(const float4*)&w_t[c * 264 + 8 * d];      // h = 0..3
    float4 w1 = *(const float4*)&w_t[c * 264 + 8 * d + 4];  // h = 4..7
    int row = g + 8 * c;
    int swz = ((row >> 4) & 3) << 2;
    float2 xv = *(const float2*)&xs[row * 18 + ((t2 * 2) ^ swz)];
    acc[0].x += w0.x * xv.x; acc[0].y += w0.x * xv.y;
    acc[1].x += w0.y * xv.x; acc[1].y += w0.y * xv.y;
    acc[2].x += w0.z * xv.x; acc[2].y += w0.z * xv.y;
    acc[3].x += w0.w * xv.x; acc[3].y += w0.w * xv.y;
    acc[4].x += w1.x * xv.x; acc[4].y += w1.x * xv.y;
    acc[5].x += w1.y * xv.x; acc[5].y += w1.y * xv.y;
    acc[6].x += w1.z * xv.x; acc[6].y += w1.z * xv.y;
    acc[7].x += w1.w * xv.x; acc[7].y += w1.w * xv.y;
  }
  int n = n0 + t2 * 2;
  if (proj < 2) {  // [bh][n][d]
#pragma unroll
    for (int h = 0; h < 8; ++h) {
      size_t o = ((size_t)((b * 8 + h) * N) + n) * D + d;
      out[o] = (_Float16)(acc[h].x * qs);
      out[o + D] = (_Float16)(acc[h].y * qs);
    }
  } else {         // V transposed: [bh][d][n]
#pragma unroll
    for (int h = 0; h < 8; ++h) {
      size_t o = ((size_t)((b * 8 + h) * D) + d) * N + n;
      out[o] = (_Float16)acc[h].x;
      out[o + 1] = (_Float16)acc[h].y;
    }
  }
}

// ---------------- kernel 3: MFMA fp16 flash attention v9 — 32 q-rows per wave ----------
// v8's staging/super-tiles/barriers EXACTLY; each wave now owns TWO 16-row q-groups
// sharing every K/V fragment read (DS per work halved, 2x ILP on softmax chains).
// Block covers 128 q-rows; grid 512 (2 blocks/CU).
__global__ __launch_bounds__(256, 2) void k_attn(
    const _Float16* __restrict__ qa, const _Float16* __restrict__ ka,
    const _Float16* __restrict__ va, float* __restrict__ op,
    float* __restrict__ mp, float* __restrict__ lp) {
  int bid = blockIdx.x;
  int r = bid & 7;          // XCD id (round-robin dispatch)
  int q = bid >> 3;         // 0..63
  int js = q >> 5;
  int bh = r * 2 + ((q >> 4) & 1);
  int rb = q & 15;          // 128 q-rows per block
  constexpr int nst = 8;    // 8 super-tiles x 128 j = 1024 j per js half

  int w = TID >> 6;
  int lane = TID & 63;
  int il = lane & 15;
  int g = lane >> 4;

  __shared__ char Kc[2][8192];  // [buf][u*4096 + swizzled 64-row K tile]
  __shared__ char Vc[2][8192];  // [buf][u*4096 + swizzled V^T tile]

  int nq0 = rb * 128 + w * 32 + il;  // group 0 row; group 1 = +16
  h8 qf[2];
  qf[0] = *(const h8*)(qa + ((size_t)bh * N + nq0) * D + g * 8);
  qf[1] = *(const h8*)(qa + ((size_t)bh * N + nq0 + 16) * D + g * 8);

  f32x4 accO[2][2];  // [grp][dh]
#pragma unroll
  for (int grp = 0; grp < 2; ++grp)
#pragma unroll
    for (int dh = 0; dh < 2; ++dh) accO[grp][dh] = (f32x4){0.f, 0.f, 0.f, 0.f};
  float m[2] = {-3.0e38f, -3.0e38f}, l[2] = {0.f, 0.f};

  // K staging: thread covers rows kj and kj+64 (same perm slot, halves 0/1)
  int kj = TID >> 2, kc = TID & 3;
  int pk = ((kj >> 5) * 2 + ((kj >> 2) & 1)) * 16 + ((kj >> 3) & 3) * 4 + (kj & 3);
  const _Float16* kbase = ka + ((size_t)bh * N + (size_t)js * 1024 + kj) * D + kc * 8;
  int kdst = (pk * 64 + kc * 16) ^ ((pk & 3) << 4);
  // V^T staging: thread covers row vd, j-chunks vc*8 and vc*8+64
  int vd = TID >> 3, vc = TID & 7;
  const _Float16* vbase = va + ((size_t)bh * D + vd) * N + (size_t)js * 1024 + vc * 8;
  int vdst = (vd * 128 + vc * 16) ^ ((vd & 7) << 4) ^ (((vd >> 3) & 3) << 5);

  // prologue: stage super-tile 0 into buffer 0
  h8 k0 = *(const h8*)kbase;
  h8 k1 = *(const h8*)(kbase + 64 * D);
  h8 v0 = *(const h8*)vbase;
  h8 v1 = *(const h8*)(vbase + 64);
  *(h8*)(Kc[0] + kdst) = k0;
  *(h8*)(Kc[0] + 4096 + kdst) = k1;
  *(h8*)(Vc[0] + vdst) = v0;
  *(h8*)(Vc[0] + 4096 + vdst) = v1;
  __syncthreads();

  // one 64-row tile: both q-groups share every K/V fragment read
  auto tile = [&](int cur, int u) {
    const char* Kt = Kc[cur] + u * 4096;
    const char* Vt = Vc[cur] + u * 4096;
    float pv[2][4][4];
    float tmax[2] = {-3.0e38f, -3.0e38f};
#pragma unroll
    for (int jt = 0; jt < 4; ++jt) {
      int krow = jt * 16 + il;
      h8 kf = *(const h8*)(Kt + ((krow * 64 + g * 16) ^ ((krow & 3) << 4)));
#pragma unroll
      for (int grp = 0; grp < 2; ++grp) {
        f32x4 accS = (f32x4){0.f, 0.f, 0.f, 0.f};
        accS = __builtin_amdgcn_mfma_f32_16x16x32_f16(kf, qf[grp], accS, 0, 0, 0);
#pragma unroll
        for (int e = 0; e < 4; ++e) {
          pv[grp][jt][e] = accS[e];
          tmax[grp] = fmaxf(tmax[grp], accS[e]);
        }
      }
    }
#pragma unroll
    for (int grp = 0; grp < 2; ++grp) {
      float tm = tmax[grp];
      tm = fmaxf(tm, __shfl_xor(tm, 16));
      tm = fmaxf(tm, __shfl_xor(tm, 32));
      if (__any(tm > m[grp])) {  // exact defer: skipped path is bit-identical
        float mn = fmaxf(m[grp], tm);
        float corr = exp2f(m[grp] - mn);
        l[grp] *= corr;
#pragma unroll
        for (int dh = 0; dh < 2; ++dh)
#pragma unroll
          for (int e = 0; e < 4; ++e) accO[grp][dh][e] *= corr;
        m[grp] = mn;
      }
      float ls = 0.f;
#pragma unroll
      for (int jt = 0; jt < 4; ++jt)
#pragma unroll
        for (int e = 0; e < 4; ++e) {
          float pe = exp2f(pv[grp][jt][e] - m[grp]);
          pv[grp][jt][e] = pe;
          ls += pe;
        }
      ls += __shfl_xor(ls, 16);
      ls += __shfl_xor(ls, 32);
      l[grp] += ls;
    }

#pragma unroll
    for (int jb = 0; jb < 2; ++jb) {
      h8 pf[2];
#pragma unroll
      for (int grp = 0; grp < 2; ++grp) {
        union { h8 v; fp16x2 p[4]; } u2;
        u2.p[0] = __builtin_amdgcn_cvt_pkrtz(pv[grp][2 * jb][0], pv[grp][2 * jb][1]);
        u2.p[1] = __builtin_amdgcn_cvt_pkrtz(pv[grp][2 * jb][2], pv[grp][2 * jb][3]);
        u2.p[2] = __builtin_amdgcn_cvt_pkrtz(pv[grp][2 * jb + 1][0], pv[grp][2 * jb + 1][1]);
        u2.p[3] = __builtin_amdgcn_cvt_pkrtz(pv[grp][2 * jb + 1][2], pv[grp][2 * jb + 1][3]);
        pf[grp] = u2.v;
      }
#pragma unroll
      for (int dh = 0; dh < 2; ++dh) {
        int vrow = dh * 16 + il;
        int vaddr = (vrow * 128 + jb * 64 + g * 16) ^ ((vrow & 7) << 4) ^
                    (((vrow >> 3) & 3) << 5);
        h8 vf = *(const h8*)(Vt + vaddr);
#pragma unroll
        for (int grp = 0; grp < 2; ++grp)
          accO[grp][dh] =
              __builtin_amdgcn_mfma_f32_16x16x32_f16(vf, pf[grp], accO[grp][dh], 0, 0, 0);
      }
    }
  };

#pragma unroll
  for (int st = 0; st < nst; ++st) {
    int cur = st & 1;
    bool more = (st + 1 < nst);
    if (more) {  // issue next super-tile global loads early
      k0 = *(const h8*)(kbase + (size_t)(st + 1) * 128 * D);
      k1 = *(const h8*)(kbase + (size_t)(st + 1) * 128 * D + 64 * D);
      v0 = *(const h8*)(vbase + (st + 1) * 128);
      v1 = *(const h8*)(vbase + (st + 1) * 128 + 64);
    }

    tile(cur, 0);
    tile(cur, 1);

    if (more) {  // write-late into the other buffer; ONE barrier per super-tile
      *(h8*)(Kc[cur ^ 1] + kdst) = k0;
      *(h8*)(Kc[cur ^ 1] + 4096 + kdst) = k1;
      *(h8*)(Vc[cur ^ 1] + vdst) = v0;
      *(h8*)(Vc[cur ^ 1] + 4096 + vdst) = v1;
      __syncthreads();
    }
  }

  // epilogue: op[(js*2+b)][n][ch], ch = h*32 + dh*16 + g*4 + e  (2x b128 per group)
  int b = bh >> 3, h = bh & 7;
#pragma unroll
  for (int grp = 0; grp < 2; ++grp) {
    int nq = nq0 + grp * 16;
    size_t obase = ((size_t)((js * 2 + b) * N) + nq) * C + h * 32;
#pragma unroll
    for (int dh = 0; dh < 2; ++dh) {
      float4 o4 = {accO[grp][dh][0], accO[grp][dh][1], accO[grp][dh][2], accO[grp][dh][3]};
      *(float4*)(op + obase + dh * 16 + g * 4) = o4;
    }
    if (g == 0) {
      size_t idx = (size_t)(js * BH + bh) * N + nq;
      mp[idx] = m[grp];
      lp[idx] = l[grp];
    }
  }
}

// ---------------- kernel 4: MFMA combine + output 1x1 conv (2-way) ----------------
__global__ __launch_bounds__(256) void k_final(const float* __restrict__ op,
    const float* __restrict__ mp, const float* __restrict__ lp,
    const float* __restrict__ wo, const float* __restrict__ bo,
    float* __restrict__ out) {
  __shared__ _Float16 woh[32 * 256];  // [o][c] swz ^((o&7)<<4) on byte addr
  __shared__ _Float16 wol[32 * 256];
  __shared__ _Float16 as_[32 * 256];  // [n][c] swz ^((n&7)<<4)
  __shared__ float cwa[8 * 32], cwb[8 * 32];
  __shared__ float bos[32];
  int nt = blockIdx.x & 63, oq = (blockIdx.x >> 6) & 7, b = blockIdx.x >> 9;
  int n0 = nt * 32, o0 = oq * 32;

  {
    int h = TID >> 5, n_l = TID & 31;
    size_t i0 = (size_t)(b * 8 + h) * N + n0 + n_l;
    size_t i1 = (size_t)(BH + b * 8 + h) * N + n0 + n_l;
    float m0 = mp[i0], m1 = mp[i1];
    float mg = fmaxf(m0, m1);
    float w0 = exp2f(m0 - mg), w1 = exp2f(m1 - mg);
    float inv = 1.f / (w0 * lp[i0] + w1 * lp[i1]);
    cwa[TID] = w0 * inv;
    cwb[TID] = w1 * inv;
  }
  if (TID < 32) bos[TID] = bo[o0 + TID];
  {
    int cc = TID & 63;
    int ob = TID >> 6;
#pragma unroll
    for (int p = 0; p < 8; ++p) {
      int o = ob + p * 4;
      float4 v = ((const float4*)wo)[(o0 + o) * 64 + cc];
      _Float16 h0 = (_Float16)v.x, h1 = (_Float16)v.y,
               h2c = (_Float16)v.z, h3 = (_Float16)v.w;
      h4 hi = {h0, h1, h2c, h3};
      h4 lo = {(_Float16)(v.x - (float)h0), (_Float16)(v.y - (float)h1),
               (_Float16)(v.z - (float)h2c), (_Float16)(v.w - (float)h3)};
      int byte = (o * 512 + cc * 8) ^ ((o & 7) << 4);
      *(h4*)((char*)woh + byte) = hi;
      *(h4*)((char*)wol + byte) = lo;
    }
  }
  __syncthreads();
  {
    int cc = TID & 63;
    int h = cc >> 3;
    int nb = TID >> 6;
#pragma unroll
    for (int p = 0; p < 8; ++p) {
      int n = nb + p * 4;
      float4 v0 = *(const float4*)(op + ((size_t)(b * N) + n0 + n) * C + cc * 4);
      float4 v1 = *(const float4*)(op + ((size_t)((2 + b) * N) + n0 + n) * C + cc * 4);
      float ca = cwa[h * 32 + n], cb = cwb[h * 32 + n];
      h4 av = {(_Float16)(ca * v0.x + cb * v1.x), (_Float16)(ca * v0.y + cb * v1.y),
               (_Float16)(ca * v0.z + cb * v1.z), (_Float16)(ca * v0.w + cb * v1.w)};
      int byte = (n * 512 + cc * 8) ^ ((n & 7) << 4);
      *(h4*)((char*)as_ + byte) = av;
    }
  }
  __syncthreads();

  int w = TID >> 6, lane = TID & 63, il = lane & 15, g = lane >> 4;
  int ow = (w & 1) * 16, nw = (w >> 1) * 16;
  f32x4 acc = (f32x4){0.f, 0.f, 0.f, 0.f};
#pragma unroll
  for (int ks = 0; ks < 8; ++ks) {
    int abyte = ((nw + il) * 512 + ks * 64 + g * 16) ^ ((il & 7) << 4);
    h8 bf = *(const h8*)((char*)as_ + abyte);
    int wbyte = ((ow + il) * 512 + ks * 64 + g * 16) ^ ((il & 7) << 4);
    h8 ah = *(const h8*)((char*)woh + wbyte);
    h8 al = *(const h8*)((char*)wol + wbyte);
    acc = __builtin_amdgcn_mfma_f32_16x16x32_f16(ah, bf, acc, 0, 0, 0);
    acc = __builtin_amdgcn_mfma_f32_16x16x32_f16(al, bf, acc, 0, 0, 0);
  }
  int n = n0 + nw + il;
#pragma unroll
  for (int r = 0; r < 4; ++r) {
    int o_l = ow + g * 4 + r;
    out[(size_t)(b * C + o0 + o_l) * N + n] = acc[r] + bos[o_l];
  }
}

extern "C" void kernel_launch(void* const* d_in, const int* in_sizes, int n_in,
                              void* d_out, int out_size, void* d_ws, size_t ws_size,
                              hipStream_t stream) {
  const float* x = (const float*)d_in[0];
  const float* gamma = (const float*)d_in[1];
  const float* beta = (const float*)d_in[2];
  const float* wk = (const float*)d_in[3];
  const float* wq = (const float*)d_in[4];
  const float* wv = (const float*)d_in[5];
  const float* wo = (const float*)d_in[6];
  const float* bo = (const float*)d_in[7];
  float* out = (float*)d_out;
  float* ws = (float*)d_ws;

  float* stats = ws;
  _Float16* qa = (_Float16*)(ws + 1024);
  _Float16* ka = qa + SZ;
  _Float16* va = ka + SZ;               // [bh][d][n] transposed
  float* op = (float*)(va + SZ);        // [js*2+b][n][ch] fp32, 2*SZ floats
  float* mp = op + 2 * SZ;              // [js*BH + bh][N]
  float* lp = mp + 2 * (size_t)BH * N;

  k_bnstats<<<256, 256, 0, stream>>>(x, gamma, beta, stats);
  k_proj<<<768, 256, 0, stream>>>(x, wk, wq, wv, stats, qa, ka, va);
  k_attn<<<512, 256, 0, stream>>>(qa, ka, va, op, mp, lp);
  k_final<<<1024, 256, 0, stream>>>(op, mp, lp, wo, bo, out);
}

// Round 23
// 58.720 us; speedup vs baseline: 1.0234x; 1.0234x over previous
//
#include <hip/hip_runtime.h>

#define TID threadIdx.x

constexpr int B = 2, C = 256, N = 2048, H = 8, D = 32, BH = 16;
constexpr float EPS = 1e-5f;
constexpr float SCL2 = 0.25505654344454694f; // 32^-0.5 * log2(e)
constexpr size_t SZ = (size_t)BH * N * D;    // 1048576 elements per Q/K/V buffer

typedef _Float16 h8 __attribute__((ext_vector_type(8)));
typedef _Float16 h4 __attribute__((ext_vector_type(4)));
typedef __fp16 fp16x2 __attribute__((ext_vector_type(2)));
typedef float f32x4 __attribute__((ext_vector_type(4)));

// ---------------- kernel 1: batchnorm stats, BN-FOLDED: a = rstd*gamma, bb = beta - mean*a
__global__ __launch_bounds__(256) void k_bnstats(const float* __restrict__ x,
                                                 const float* __restrict__ gamma,
                                                 const float* __restrict__ beta,
                                                 float* __restrict__ stats) {
  int c = blockIdx.x;
  float s = 0.f, ss = 0.f;
  const float4* x4 = (const float4*)x;
  for (int k = 0; k < B; ++k) {
    const float4* p = x4 + (size_t)(k * C + c) * (N / 4);
    for (int i = TID; i < N / 4; i += 256) {
      float4 v = p[i];
      s += v.x + v.y + v.z + v.w;
      ss += v.x * v.x + v.y * v.y + v.z * v.z + v.w * v.w;
    }
  }
#pragma unroll
  for (int off = 32; off; off >>= 1) {
    s += __shfl_down(s, off);
    ss += __shfl_down(ss, off);
  }
  __shared__ float red[8];
  int w = TID >> 6;
  if ((TID & 63) == 0) { red[w] = s; red[4 + w] = ss; }
  __syncthreads();
  if (TID == 0) {
    float S = red[0] + red[1] + red[2] + red[3];
    float SS = red[4] + red[5] + red[6] + red[7];
    float mean = S * (1.f / (B * N));
    float var = SS * (1.f / (B * N)) - mean * mean;
    float a = rsqrtf(var + EPS) * gamma[c];
    stats[c] = a;
    stats[C + c] = beta[c] - mean * a;
  }
}

// ---------------- kernel 2: proj v3 — DS-minimized; Q pre-scaled by SCL2 ----------------
__global__ __launch_bounds__(256) void k_proj(const float* __restrict__ x,
    const float* __restrict__ wk, const float* __restrict__ wq,
    const float* __restrict__ wv, const float* __restrict__ stats,
    _Float16* __restrict__ qa, _Float16* __restrict__ ka, _Float16* __restrict__ va) {
  int proj = blockIdx.x >> 8;
  int rem = blockIdx.x & 255;
  int b = rem >> 7;
  int n0 = (rem & 127) * 16;
  const float* w = proj == 0 ? wk : (proj == 1 ? wq : wv);
  _Float16* out = proj == 0 ? qa : (proj == 1 ? ka : va);
  float qs = (proj == 0) ? SCL2 : 1.0f;  // fold attention scale into Q

  __shared__ float w_t[32 * 264];  // [c][ch] transposed weights (+8 pad)
  __shared__ float xs[256 * 18];   // row (g+8c); col' = col ^ ((((row)>>4)&3)<<2)
  __shared__ float sab[512];       // a[c], bb[c]

  sab[TID] = stats[TID];
  sab[256 + TID] = stats[256 + TID];
  {
    const float4* wr4 = (const float4*)(w + TID * 32);
#pragma unroll
    for (int p = 0; p < 8; ++p) {
      float4 v = wr4[p];
      w_t[(p * 4 + 0) * 264 + TID] = v.x;
      w_t[(p * 4 + 1) * 264 + TID] = v.y;
      w_t[(p * 4 + 2) * 264 + TID] = v.z;
      w_t[(p * 4 + 3) * 264 + TID] = v.w;
    }
  }
  __syncthreads();
#pragma unroll
  for (int p = 0; p < 4; ++p) {
    int c = p * 64 + (TID >> 2);
    int n4 = (TID & 3) * 4;
    float4 v = *(const float4*)(x + (size_t)(b * C + c) * N + n0 + n4);
    float a = sab[c], bb = sab[256 + c];
    int row = (c >> 5) + ((c & 31) << 3);  // g + 8c
    int swz = ((row >> 4) & 3) << 2;
    float2 lo = {v.x * a + bb, v.y * a + bb};
    float2 hi = {v.z * a + bb, v.w * a + bb};
    *(float2*)&xs[row * 18 + (n4 ^ swz)] = lo;
    *(float2*)&xs[row * 18 + ((n4 + 2) ^ swz)] = hi;
  }
  __syncthreads();

  int d = TID & 31, t2 = TID >> 5;
  int g = d >> 2;  // channel group, h-invariant
  float2 acc[8];
#pragma unroll
  for (int h = 0; h < 8; ++h) acc[h] = (float2){0.f, 0.f};
#pragma unroll
  for (int c = 0; c < 32; ++c) {
    float4 w0 = *(const float4*)&w_t[c * 264 + 8 * d];      // h = 0..3
    float4 w1 = *(const float4*)&w_t[c * 264 + 8 * d + 4];  // h = 4..7
    int row = g + 8 * c;
    int swz = ((row >> 4) & 3) << 2;
    float2 xv = *(const float2*)&xs[row * 18 + ((t2 * 2) ^ swz)];
    acc[0].x += w0.x * xv.x; acc[0].y += w0.x * xv.y;
    acc[1].x += w0.y * xv.x; acc[1].y += w0.y * xv.y;
    acc[2].x += w0.z * xv.x; acc[2].y += w0.z * xv.y;
    acc[3].x += w0.w * xv.x; acc[3].y += w0.w * xv.y;
    acc[4].x += w1.x * xv.x; acc[4].y += w1.x * xv.y;
    acc[5].x += w1.y * xv.x; acc[5].y += w1.y * xv.y;
    acc[6].x += w1.z * xv.x; acc[6].y += w1.z * xv.y;
    acc[7].x += w1.w * xv.x; acc[7].y += w1.w * xv.y;
  }
  int n = n0 + t2 * 2;
  if (proj < 2) {  // [bh][n][d]
#pragma unroll
    for (int h = 0; h < 8; ++h) {
      size_t o = ((size_t)((b * 8 + h) * N) + n) * D + d;
      out[o] = (_Float16)(acc[h].x * qs);
      out[o + D] = (_Float16)(acc[h].y * qs);
    }
  } else {         // V transposed: [bh][d][n]
#pragma unroll
    for (int h = 0; h < 8; ++h) {
      size_t o = ((size_t)((b * 8 + h) * D) + d) * N + n;
      out[o] = (_Float16)acc[h].x;
      out[o + 1] = (_Float16)acc[h].y;
    }
  }
}

// ---------------- kernel 3: MFMA fp16 flash attention v8 ----------------
// Dual-state, defer-rescale, pkrtz, permuted-K (no P round-trip), 128-row
// super-tiles (1 barrier each), write-late dbuf. LDS 32 KB, 4 blocks/CU.
__global__ __launch_bounds__(256, 4) void k_attn(
    const _Float16* __restrict__ qa, const _Float16* __restrict__ ka,
    const _Float16* __restrict__ va, float* __restrict__ op,
    float* __restrict__ mp, float* __restrict__ lp) {
  int bid = blockIdx.x;
  int r = bid & 7;          // XCD id (round-robin dispatch)
  int q = bid >> 3;         // 0..127
  int js = q >> 6;
  int bh = r * 2 + ((q >> 5) & 1);
  int rb = q & 31;
  constexpr int nst = 8;    // 8 super-tiles x 128 j = 1024 j per js half

  int w = TID >> 6;
  int lane = TID & 63;
  int il = lane & 15;
  int g = lane >> 4;

  __shared__ char Kc[2][8192];  // [buf][u*4096 + swizzled 64-row K tile]
  __shared__ char Vc[2][8192];  // [buf][u*4096 + swizzled V^T tile]

  int n_q = rb * 64 + w * 16 + il;
  h8 qf = *(const h8*)(qa + ((size_t)bh * N + n_q) * D + g * 8);

  f32x4 accO0[2], accO1[2];
#pragma unroll
  for (int dh = 0; dh < 2; ++dh) {
    accO0[dh] = (f32x4){0.f, 0.f, 0.f, 0.f};
    accO1[dh] = (f32x4){0.f, 0.f, 0.f, 0.f};
  }
  float m0 = -3.0e38f, l0 = 0.f, m1 = -3.0e38f, l1 = 0.f;

  // K staging: thread covers rows kj and kj+64 (same perm slot, halves 0/1)
  int kj = TID >> 2, kc = TID & 3;
  int pk = ((kj >> 5) * 2 + ((kj >> 2) & 1)) * 16 + ((kj >> 3) & 3) * 4 + (kj & 3);
  const _Float16* kbase = ka + ((size_t)bh * N + (size_t)js * 1024 + kj) * D + kc * 8;
  int kdst = (pk * 64 + kc * 16) ^ ((pk & 3) << 4);
  // V^T staging: thread covers row vd, j-chunks vc*8 and vc*8+64
  int vd = TID >> 3, vc = TID & 7;
  const _Float16* vbase = va + ((size_t)bh * D + vd) * N + (size_t)js * 1024 + vc * 8;
  int vdst = (vd * 128 + vc * 16) ^ ((vd & 7) << 4) ^ (((vd >> 3) & 3) << 5);

  // prologue: stage super-tile 0 into buffer 0
  h8 k0 = *(const h8*)kbase;
  h8 k1 = *(const h8*)(kbase + 64 * D);
  h8 v0 = *(const h8*)vbase;
  h8 v1 = *(const h8*)(vbase + 64);
  *(h8*)(Kc[0] + kdst) = k0;
  *(h8*)(Kc[0] + 4096 + kdst) = k1;
  *(h8*)(Vc[0] + vdst) = v0;
  *(h8*)(Vc[0] + 4096 + vdst) = v1;
  __syncthreads();

  // one 64-row tile
  auto tile = [&](int cur, int u, float& m, float& l, f32x4* accO) {
    const char* Kt = Kc[cur] + u * 4096;
    const char* Vt = Vc[cur] + u * 4096;
    float pv[4][4];
    float tmax = -3.0e38f;
#pragma unroll
    for (int jt = 0; jt < 4; ++jt) {
      int krow = jt * 16 + il;
      h8 kf = *(const h8*)(Kt + ((krow * 64 + g * 16) ^ ((krow & 3) << 4)));
      f32x4 accS = (f32x4){0.f, 0.f, 0.f, 0.f};
      accS = __builtin_amdgcn_mfma_f32_16x16x32_f16(kf, qf, accS, 0, 0, 0);
#pragma unroll
      for (int e = 0; e < 4; ++e) {
        pv[jt][e] = accS[e];
        tmax = fmaxf(tmax, accS[e]);
      }
    }
    tmax = fmaxf(tmax, __shfl_xor(tmax, 16));
    tmax = fmaxf(tmax, __shfl_xor(tmax, 32));
    if (__any(tmax > m)) {  // exact defer: skipped path is bit-identical (corr=1)
      float mn = fmaxf(m, tmax);
      float corr = exp2f(m - mn);
      l *= corr;
#pragma unroll
      for (int dh = 0; dh < 2; ++dh)
#pragma unroll
        for (int e = 0; e < 4; ++e) accO[dh][e] *= corr;
      m = mn;
    }
    float ls = 0.f;
#pragma unroll
    for (int jt = 0; jt < 4; ++jt)
#pragma unroll
      for (int e = 0; e < 4; ++e) {
        float pe = exp2f(pv[jt][e] - m);
        pv[jt][e] = pe;
        ls += pe;
      }
    ls += __shfl_xor(ls, 16);
    ls += __shfl_xor(ls, 32);
    l += ls;

#pragma unroll
    for (int jb = 0; jb < 2; ++jb) {
      union { h8 v; fp16x2 p[4]; } u2;
      u2.p[0] = __builtin_amdgcn_cvt_pkrtz(pv[2 * jb][0], pv[2 * jb][1]);
      u2.p[1] = __builtin_amdgcn_cvt_pkrtz(pv[2 * jb][2], pv[2 * jb][3]);
      u2.p[2] = __builtin_amdgcn_cvt_pkrtz(pv[2 * jb + 1][0], pv[2 * jb + 1][1]);
      u2.p[3] = __builtin_amdgcn_cvt_pkrtz(pv[2 * jb + 1][2], pv[2 * jb + 1][3]);
#pragma unroll
      for (int dh = 0; dh < 2; ++dh) {
        int vrow = dh * 16 + il;
        int vaddr = (vrow * 128 + jb * 64 + g * 16) ^ ((vrow & 7) << 4) ^
                    (((vrow >> 3) & 3) << 5);
        h8 vf = *(const h8*)(Vt + vaddr);
        accO[dh] = __builtin_amdgcn_mfma_f32_16x16x32_f16(vf, u2.v, accO[dh], 0, 0, 0);
      }
    }
  };

#pragma unroll
  for (int st = 0; st < nst; ++st) {
    int cur = st & 1;
    bool more = (st + 1 < nst);
    if (more) {  // issue next super-tile global loads early (2-tile compute cover)
      k0 = *(const h8*)(kbase + (size_t)(st + 1) * 128 * D);
      k1 = *(const h8*)(kbase + (size_t)(st + 1) * 128 * D + 64 * D);
      v0 = *(const h8*)(vbase + (st + 1) * 128);
      v1 = *(const h8*)(vbase + (st + 1) * 128 + 64);
    }

    tile(cur, 0, m0, l0, accO0);  // global tile 2*st   (even -> state 0)
    tile(cur, 1, m1, l1, accO1);  // global tile 2*st+1 (odd  -> state 1)

    if (more) {  // write-late into the other buffer; ONE barrier per super-tile
      *(h8*)(Kc[cur ^ 1] + kdst) = k0;
      *(h8*)(Kc[cur ^ 1] + 4096 + kdst) = k1;
      *(h8*)(Vc[cur ^ 1] + vdst) = v0;
      *(h8*)(Vc[cur ^ 1] + 4096 + vdst) = v1;
      __syncthreads();
    }
  }

  // merge the two softmax states
  float m = fmaxf(m0, m1);
  float c0 = exp2f(m0 - m), c1 = exp2f(m1 - m);
  float l = l0 * c0 + l1 * c1;
  f32x4 accO[2];
#pragma unroll
  for (int dh = 0; dh < 2; ++dh)
#pragma unroll
    for (int e = 0; e < 4; ++e)
      accO[dh][e] = accO0[dh][e] * c0 + accO1[dh][e] * c1;

  // epilogue: op[(js*2+b)][n_q][ch], ch = h*32 + dh*16 + g*4 + e  (2x b128)
  int b = bh >> 3, h = bh & 7;
  size_t obase = ((size_t)((js * 2 + b) * N) + n_q) * C + h * 32;
#pragma unroll
  for (int dh = 0; dh < 2; ++dh) {
    float4 o4 = {accO[dh][0], accO[dh][1], accO[dh][2], accO[dh][3]};
    *(float4*)(op + obase + dh * 16 + g * 4) = o4;
  }
  if (g == 0) {
    size_t idx = (size_t)(js * BH + bh) * N + n_q;
    mp[idx] = m;
    lp[idx] = l;
  }
}

// ---------------- kernel 4: MFMA combine + output 1x1 conv (2-way) ----------------
__global__ __launch_bounds__(256) void k_final(const float* __restrict__ op,
    const float* __restrict__ mp, const float* __restrict__ lp,
    const float* __restrict__ wo, const float* __restrict__ bo,
    float* __restrict__ out) {
  __shared__ _Float16 woh[32 * 256];  // [o][c] swz ^((o&7)<<4) on byte addr
  __shared__ _Float16 wol[32 * 256];
  __shared__ _Float16 as_[32 * 256];  // [n][c] swz ^((n&7)<<4)
  __shared__ float cwa[8 * 32], cwb[8 * 32];
  __shared__ float bos[32];
  int nt = blockIdx.x & 63, oq = (blockIdx.x >> 6) & 7, b = blockIdx.x >> 9;
  int n0 = nt * 32, o0 = oq * 32;

  {
    int h = TID >> 5, n_l = TID & 31;
    size_t i0 = (size_t)(b * 8 + h) * N + n0 + n_l;
    size_t i1 = (size_t)(BH + b * 8 + h) * N + n0 + n_l;
    float m0 = mp[i0], m1 = mp[i1];
    float mg = fmaxf(m0, m1);
    float w0 = exp2f(m0 - mg), w1 = exp2f(m1 - mg);
    float inv = 1.f / (w0 * lp[i0] + w1 * lp[i1]);
    cwa[TID] = w0 * inv;
    cwb[TID] = w1 * inv;
  }
  if (TID < 32) bos[TID] = bo[o0 + TID];
  {
    int cc = TID & 63;
    int ob = TID >> 6;
#pragma unroll
    for (int p = 0; p < 8; ++p) {
      int o = ob + p * 4;
      float4 v = ((const float4*)wo)[(o0 + o) * 64 + cc];
      _Float16 h0 = (_Float16)v.x, h1 = (_Float16)v.y,
               h2c = (_Float16)v.z, h3 = (_Float16)v.w;
      h4 hi = {h0, h1, h2c, h3};
      h4 lo = {(_Float16)(v.x - (float)h0), (_Float16)(v.y - (float)h1),
               (_Float16)(v.z - (float)h2c), (_Float16)(v.w - (float)h3)};
      int byte = (o * 512 + cc * 8) ^ ((o & 7) << 4);
      *(h4*)((char*)woh + byte) = hi;
      *(h4*)((char*)wol + byte) = lo;
    }
  }
  __syncthreads();
  {
    int cc = TID & 63;
    int h = cc >> 3;
    int nb = TID >> 6;
#pragma unroll
    for (int p = 0; p < 8; ++p) {
      int n = nb + p * 4;
      float4 v0 = *(const float4*)(op + ((size_t)(b * N) + n0 + n) * C + cc * 4);
      float4 v1 = *(const float4*)(op + ((size_t)((2 + b) * N) + n0 + n) * C + cc * 4);
      float ca = cwa[h * 32 + n], cb = cwb[h * 32 + n];
      h4 av = {(_Float16)(ca * v0.x + cb * v1.x), (_Float16)(ca * v0.y + cb * v1.y),
               (_Float16)(ca * v0.z + cb * v1.z), (_Float16)(ca * v0.w + cb * v1.w)};
      int byte = (n * 512 + cc * 8) ^ ((n & 7) << 4);
      *(h4*)((char*)as_ + byte) = av;
    }
  }
  __syncthreads();

  int w = TID >> 6, lane = TID & 63, il = lane & 15, g = lane >> 4;
  int ow = (w & 1) * 16, nw = (w >> 1) * 16;
  f32x4 acc = (f32x4){0.f, 0.f, 0.f, 0.f};
#pragma unroll
  for (int ks = 0; ks < 8; ++ks) {
    int abyte = ((nw + il) * 512 + ks * 64 + g * 16) ^ ((il & 7) << 4);
    h8 bf = *(const h8*)((char*)as_ + abyte);
    int wbyte = ((ow + il) * 512 + ks * 64 + g * 16) ^ ((il & 7) << 4);
    h8 ah = *(const h8*)((char*)woh + wbyte);
    h8 al = *(const h8*)((char*)wol + wbyte);
    acc = __builtin_amdgcn_mfma_f32_16x16x32_f16(ah, bf, acc, 0, 0, 0);
    acc = __builtin_amdgcn_mfma_f32_16x16x32_f16(al, bf, acc, 0, 0, 0);
  }
  int n = n0 + nw + il;
#pragma unroll
  for (int r = 0; r < 4; ++r) {
    int o_l = ow + g * 4 + r;
    out[(size_t)(b * C + o0 + o_l) * N + n] = acc[r] + bos[o_l];
  }
}

extern "C" void kernel_launch(void* const* d_in, const int* in_sizes, int n_in,
                              void* d_out, int out_size, void* d_ws, size_t ws_size,
                              hipStream_t stream) {
  const float* x = (const float*)d_in[0];
  const float* gamma = (const float*)d_in[1];
  const float* beta = (const float*)d_in[2];
  const float* wk = (const float*)d_in[3];
  const float* wq = (const float*)d_in[4];
  const float* wv = (const float*)d_in[5];
  const float* wo = (const float*)d_in[6];
  const float* bo = (const float*)d_in[7];
  float* out = (float*)d_out;
  float* ws = (float*)d_ws;

  float* stats = ws;
  _Float16* qa = (_Float16*)(ws + 1024);
  _Float16* ka = qa + SZ;
  _Float16* va = ka + SZ;               // [bh][d][n] transposed
  float* op = (float*)(va + SZ);        // [js*2+b][n][ch] fp32, 2*SZ floats
  float* mp = op + 2 * SZ;              // [js*BH + bh][N]
  float* lp = mp + 2 * (size_t)BH * N;

  k_bnstats<<<256, 256, 0, stream>>>(x, gamma, beta, stats);
  k_proj<<<768, 256, 0, stream>>>(x, wk, wq, wv, stats, qa, ka, va);
  k_attn<<<1024, 256, 0, stream>>>(qa, ka, va, op, mp, lp);
  k_final<<<1024, 256, 0, stream>>>(op, mp, lp, wo, bo, out);
}